// Round 2
// baseline (112.541 us; speedup 1.0000x reference)
//
#include <hip/hip_runtime.h>

// Problem constants (reference: B=32, L=64, C=4)
#define BB 32
#define LL 64
#define LC 256
#define NPAIR 2016
#define PPB 4                 // pairs per block
#define NBLK (NPAIR / PPB)    // 504 blocks ~= 2 per CU

// v3: NO workspace use at all. The 256 MiB d_ws re-poison fill
// (~41 us at 6.5 TB/s, seen as fillBufferAligned in rocprof top-5) dominated
// the timed graph; our kernels were <40 us combined. Structure:
//   init_kernel : out[b] = theta0 + sum_l theta1[l, c_bl]   (zero-ws init)
//   pair_kernel : 504 blocks x 4 pairs, per-b partial -> one atomicAdd per
//                 (block, b). 16K device-scope atomics over 2 lines ~= 2-6 us,
//                 replacing the 258 KB ws round-trip + reduce kernel.
// Codes c[w] are computed once per BLOCK (not per pair) -> 4x less argmax
// VALU than the per-pair version.

__global__ __launch_bounds__(256) void init_kernel(
    const float* __restrict__ x, const float* __restrict__ t0,
    const float* __restrict__ t1, float* __restrict__ out)
{
    const int tid = threadIdx.x;
    const int b = tid >> 3, k = tid & 7;
    const float4* __restrict__ x4 = (const float4*)x + b * 64;
    float s = 0.0f;
#pragma unroll
    for (int m = 0; m < 8; ++m) {
        const int l = 8 * m + k;
        float4 f = x4[l];
        int c = 0; float best = f.x;
        if (f.y > best) { best = f.y; c = 1; }
        if (f.z > best) { best = f.z; c = 2; }
        if (f.w > best) { best = f.w; c = 3; }
        s += t1[4 * l + c];
    }
    s += __shfl_down(s, 4, 8);
    s += __shfl_down(s, 2, 8);
    s += __shfl_down(s, 1, 8);
    if (k == 0) out[b] = s + t0[0];
}

__global__ __launch_bounds__(256) void pair_kernel(
    const float* __restrict__ x, const float* __restrict__ t2,
    const float* __restrict__ t3, float* __restrict__ out)
{
    const int tid = threadIdx.x;
    const int b = tid >> 3, k = tid & 7;
    const float4* __restrict__ x4 = (const float4*)x + b * 64;

    // codes for my 8 w's (w = 8m+k): once per block, reused across PPB pairs
    int c[8];
#pragma unroll
    for (int m = 0; m < 8; ++m) {
        float4 f = x4[8 * m + k];
        int ci = 0; float best = f.x;
        if (f.y > best) { best = f.y; ci = 1; }
        if (f.z > best) { best = f.z; ci = 2; }
        if (f.w > best) { best = f.w; ci = 3; }
        c[m] = ci;
    }

    // decode first pair index t = v*(v-1)/2 + u of this block
    const int tp0 = blockIdx.x * PPB;
    int v = (int)((1.0f + sqrtf(8.0f * (float)tp0 + 1.0f)) * 0.5f);
    while (v * (v - 1) / 2 > tp0) --v;
    while ((v + 1) * v / 2 <= tp0) ++v;
    int u = tp0 - v * (v - 1) / 2;

    float acc = 0.0f;
#pragma unroll
    for (int i = 0; i < PPB; ++i) {
        float4 fu = x4[u], fv = x4[v];   // L1 broadcast (u,v block-uniform)
        int cu = 0; { float bst = fu.x;
            if (fu.y > bst) { bst = fu.y; cu = 1; }
            if (fu.z > bst) { bst = fu.z; cu = 2; }
            if (fu.w > bst) { bst = fu.w; cu = 3; } }
        int cv = 0; { float bst = fv.x;
            if (fv.y > bst) { bst = fv.y; cv = 1; }
            if (fv.z > bst) { bst = fv.z; cv = 2; }
            if (fv.w > bst) { bst = fv.w; cv = 3; } }
        const int pu = 4 * u + cu, pv = 4 * v + cv;

        const float4* __restrict__ row4 =
            (const float4*)(t3 + ((size_t)pu << 16) + ((size_t)pv << 8));
        if (k == 0) acc += t2[pu * LC + pv];   // theta2 term, once per (b,pair)

#pragma unroll
        for (int m = 0; m < 8; ++m) {
            const int w = 8 * m + k;
            float4 f = row4[w];                 // coalesced 16B, in-bounds
            const int ci = c[m];
            float lo = (ci & 1) ? f.y : f.x;    // cndmask chain, no scratch
            float hi = (ci & 1) ? f.w : f.z;
            float val = (ci & 2) ? hi : lo;
            acc += (w > v) ? val : 0.0f;        // strict-triangle mask
        }

        // next pair in triangular order
        ++u; if (u == v) { u = 0; ++v; }
    }

    // width-8 shuffle reduce over k, then one atomic per (block, b)
    acc += __shfl_down(acc, 4, 8);
    acc += __shfl_down(acc, 2, 8);
    acc += __shfl_down(acc, 1, 8);
    if (k == 0) atomicAdd(&out[b], acc);
}

extern "C" void kernel_launch(void* const* d_in, const int* in_sizes, int n_in,
                              void* d_out, int out_size, void* d_ws, size_t ws_size,
                              hipStream_t stream) {
    const float* x  = (const float*)d_in[0];  // (B, L*C)
    const float* t0 = (const float*)d_in[1];  // (1,)
    const float* t1 = (const float*)d_in[2];  // (L, C)
    const float* t2 = (const float*)d_in[3];  // (L, C, L, C)
    const float* t3 = (const float*)d_in[4];  // (L, C, L, C, L, C)
    float* out = (float*)d_out;               // (B, 1)
    (void)d_ws; (void)ws_size;                // workspace deliberately unused

    init_kernel<<<1, 256, 0, stream>>>(x, t0, t1, out);
    pair_kernel<<<NBLK, 256, 0, stream>>>(x, t2, t3, out);
}